// Round 3
// baseline (377.581 us; speedup 1.0000x reference)
//
#include <hip/hip_runtime.h>
#include <stdint.h>

#define N_TOK 4096
#define DIM   1024
#define NCLS  32000
#define IGNIDX (-100)
#define BM 256
#define BN 256
#define BK 64
#define NTN (NCLS / BN)     // 125 col-tiles
#define NTM (N_TOK / BM)    // 16 row-tiles
#define KT  (DIM / BK)      // 16 K-tiles

typedef float  f32x4  __attribute__((ext_vector_type(4)));
typedef __bf16 bf16x8 __attribute__((ext_vector_type(8)));
typedef unsigned short u16;
typedef u16 u16x8 __attribute__((ext_vector_type(8)));

#define GLDS(g, s) __builtin_amdgcn_global_load_lds( \
    (__attribute__((address_space(1))) void*)(g),    \
    (__attribute__((address_space(3))) void*)(s), 16, 0, 0)
#define LGKM0 asm volatile("s_waitcnt lgkmcnt(0)" ::: "memory")
#define VMCNT8 asm volatile("s_waitcnt vmcnt(8)" ::: "memory")
#define VMCNT0 asm volatile("s_waitcnt vmcnt(0)" ::: "memory")
#define FENCE asm volatile("" ::: "memory")

__device__ __forceinline__ u16 f2bf(float f) {
  union { float f; uint32_t u; } c; c.f = f;
  uint32_t u = c.u;
  return (u16)((u + 0x7fffu + ((u >> 16) & 1u)) >> 16);  // RNE
}

// ---- fp32 -> bf16 bulk convert ----
__global__ void cvt_bf16(const float4* __restrict__ in, u16x8* __restrict__ out, int n8) {
  int i = blockIdx.x * 256 + threadIdx.x;
  if (i >= n8) return;
  float4 a = in[2 * i], b = in[2 * i + 1];
  u16x8 o;
  o[0] = f2bf(a.x); o[1] = f2bf(a.y); o[2] = f2bf(a.z); o[3] = f2bf(a.w);
  o[4] = f2bf(b.x); o[5] = f2bf(b.y); o[6] = f2bf(b.z); o[7] = f2bf(b.w);
  out[i] = o;
}

// ---- effective targets, ignore flags, divisor ----
__global__ void prep_targ(const int* __restrict__ targ, int* __restrict__ teff,
                          int* __restrict__ ign, float* __restrict__ divisor) {
  __shared__ int cnt[16];
  int local = 0;
  for (int i = threadIdx.x; i < N_TOK; i += 1024) {
    int t = targ[i];
    if (t != IGNIDX) local++;
    int pos = i & (N_TOK / 4 - 1);
    int te;
    if (pos < N_TOK / 4 - 1)      te = targ[i + 1];
    else if (i == N_TOK - 1)      te = IGNIDX;
    else                          te = targ[i + 2];
    ign[i] = (te == IGNIDX) ? 1 : 0;
    te = te < 0 ? 0 : (te > NCLS - 1 ? NCLS - 1 : te);
    teff[i] = te;
  }
#pragma unroll
  for (int d = 1; d < 64; d <<= 1) local += __shfl_xor(local, d);
  if ((threadIdx.x & 63) == 0) cnt[threadIdx.x >> 6] = local;
  __syncthreads();
  if (threadIdx.x == 0) {
    int t = 0;
    for (int i = 0; i < 16; i++) t += cnt[i];
    divisor[0] = (float)t;
  }
}

// stage 8 LDS rows starting at rb8 (multiple of 8): one gload_lds per thread.
// linear LDS dest; inverse-swizzled global source (slot s holds col-granule s^(r&7)).
__device__ __forceinline__ void stage8(const u16* srcTile, u16* ldsTile, int rb8, int l) {
  const int lr = l >> 3;
  const int lc = (l & 7) ^ lr;
  GLDS(srcTile + (size_t)(rb8 + lr) * DIM + lc * 8, ldsTile + (size_t)rb8 * BK);
}

template <int P>
__device__ __forceinline__ void ds_loads(const u16* Ac, const u16* Bc, int wm, int wn,
                                         int lo, int hi, int key,
                                         bf16x8 (&af)[4][2], bf16x8 (&bfv)[2][2]) {
  const int mB = (P >> 1) * 4, nB = (P & 1) * 2;
#pragma unroll
  for (int mm = 0; mm < 4; mm++) {
    const int r = wm * 128 + (mB + mm) * 16 + lo;
#pragma unroll
    for (int kk = 0; kk < 2; kk++)
      af[mm][kk] = *(const bf16x8*)&Ac[(size_t)r * BK + ((((kk << 2) | hi)) ^ key) * 8];
  }
#pragma unroll
  for (int nn = 0; nn < 2; nn++) {
    const int r = wn * 64 + (nB + nn) * 16 + lo;
#pragma unroll
    for (int kk = 0; kk < 2; kk++)
      bfv[nn][kk] = *(const bf16x8*)&Bc[(size_t)r * BK + ((((kk << 2) | hi)) ^ key) * 8];
  }
}

template <int P>
__device__ __forceinline__ void do_mfma(f32x4 (&acc)[8][4], const bf16x8 (&af)[4][2],
                                        const bf16x8 (&bfv)[2][2]) {
  const int mB = (P >> 1) * 4, nB = (P & 1) * 2;
  __builtin_amdgcn_s_setprio(1);
#pragma unroll
  for (int mm = 0; mm < 4; mm++)
#pragma unroll
    for (int nn = 0; nn < 2; nn++)
#pragma unroll
      for (int kk = 0; kk < 2; kk++)
        acc[mB + mm][nB + nn] = __builtin_amdgcn_mfma_f32_16x16x32_bf16(
            af[mm][kk], bfv[nn][kk], acc[mB + mm][nB + nn], 0, 0, 0);
  __builtin_amdgcn_s_setprio(0);
}

// ---- fused 256x256 counted-vmcnt pipelined GEMM + per-tile sum(exp) partials ----
__launch_bounds__(512, 2)
__global__ void gemm_lse(const u16* __restrict__ Xb, const u16* __restrict__ Wb,
                         const int* __restrict__ teff, float* __restrict__ gt,
                         float* __restrict__ partial) {
  __shared__ u16 Abuf[2][BM][BK];   // 64 KiB
  __shared__ u16 Bbuf[2][BN][BK];   // 64 KiB

  const int tid = threadIdx.x;
  const int w = tid >> 6, l = tid & 63;
  const int wm = w >> 2, wn = w & 3;          // 2 x 4 wave grid
  const int hi = l >> 4, lo = l & 15;
  const int key = l & 7;
  const int w8 = w * 8;
  const int rb2 = (w >> 2) * 64 + (w & 3) * 8;   // S2 base rows
  const int rb3 = rb2 + 32;                      // S3 base rows

  // XCD-chunked bijective swizzle (2000 % 8 == 0)
  const int bid = blockIdx.x;
  const int wg = (bid & 7) * (NTM * NTN / 8) + (bid >> 3);
  const int bx = wg & (NTM - 1), by = wg >> 4;
  const int rowBase = bx * BM, colBase = by * BN;

  const u16* Asrc = Xb + (size_t)rowBase * DIM;
  const u16* Bsrc = Wb + (size_t)colBase * DIM;

  f32x4 acc[8][4] = {};

  u16* A0 = &Abuf[0][0][0]; u16* A1 = &Abuf[1][0][0];
  u16* B0 = &Bbuf[0][0][0]; u16* B1 = &Bbuf[1][0][0];

  // ---- prologue: seq = S0(0), S2(0), S3(0), S1(0), S0(1), S2(1) ----
  stage8(Asrc, A0, w8, l);            stage8(Asrc, A0, 128 + w8, l);        // S0(0)
  stage8(Bsrc, B0, rb2, l);           stage8(Bsrc, B0, rb2 + 128, l);       // S2(0)
  stage8(Bsrc, B0, rb3, l);           stage8(Bsrc, B0, rb3 + 128, l);       // S3(0)
  stage8(Asrc, A0, 64 + w8, l);       stage8(Asrc, A0, 192 + w8, l);        // S1(0)
  stage8(Asrc + BK, A1, w8, l);       stage8(Asrc + BK, A1, 128 + w8, l);   // S0(1)
  stage8(Bsrc + BK, B1, rb2, l);      stage8(Bsrc + BK, B1, rb2 + 128, l);  // S2(1)
  VMCNT8;  // oldest 4 loads (S0(0), S2(0)) complete
  FENCE;
  __builtin_amdgcn_s_barrier();

  for (int t = 0; t < KT; t++) {
    const int cur = t & 1;
    const u16* Ac = cur ? A1 : A0;  const u16* Bc = cur ? B1 : B0;
    u16* An = cur ? A0 : A1;        u16* Bn = cur ? B0 : B1;
    u16* Acw = cur ? A1 : A0;       u16* Bcw = cur ? B1 : B0;
    const int t1 = (t + 1) & (KT - 1);
    const int t2 = (t + 2) & (KT - 1);
    const u16* As1 = Asrc + t1 * BK; const u16* Bs1 = Bsrc + t1 * BK;
    const u16* As2 = Asrc + t2 * BK; const u16* Bs2 = Bsrc + t2 * BK;

    bf16x8 af[4][2], bfv[2][2];

    // ---- p0: reads S0(A) + S2(B); issue S3(t+1) -> other buf ----
    ds_loads<0>(Ac, Bc, wm, wn, lo, hi, key, af, bfv);
    stage8(Bs1, Bn, rb3, l); stage8(Bs1, Bn, rb3 + 128, l);
    FENCE; __builtin_amdgcn_s_barrier();
    LGKM0; __builtin_amdgcn_sched_barrier(0);
    do_mfma<0>(acc, af, bfv);
    VMCNT8; FENCE; __builtin_amdgcn_s_barrier();

    // ---- p1: reads S0(A) + S3(B); issue S1(t+1) -> other buf ----
    ds_loads<1>(Ac, Bc, wm, wn, lo, hi, key, af, bfv);
    stage8(As1, An, 64 + w8, l); stage8(As1, An, 192 + w8, l);
    FENCE; __builtin_amdgcn_s_barrier();
    LGKM0; __builtin_amdgcn_sched_barrier(0);
    do_mfma<1>(acc, af, bfv);
    VMCNT8; FENCE; __builtin_amdgcn_s_barrier();

    // ---- p2: reads S1(A) + S2(B); issue S0(t+2) -> CURRENT buf (S0 free after p1) ----
    ds_loads<2>(Ac, Bc, wm, wn, lo, hi, key, af, bfv);
    stage8(As2, Acw, w8, l); stage8(As2, Acw, 128 + w8, l);
    FENCE; __builtin_amdgcn_s_barrier();
    LGKM0; __builtin_amdgcn_sched_barrier(0);
    do_mfma<2>(acc, af, bfv);
    FENCE; __builtin_amdgcn_s_barrier();          // no vmcnt here

    // ---- p3: reads S1(A) + S3(B); issue S2(t+2) -> CURRENT buf (S2 free after p2) ----
    ds_loads<3>(Ac, Bc, wm, wn, lo, hi, key, af, bfv);
    stage8(Bs2, Bcw, rb2, l); stage8(Bs2, Bcw, rb2 + 128, l);
    FENCE; __builtin_amdgcn_s_barrier();
    LGKM0; __builtin_amdgcn_sched_barrier(0);
    do_mfma<3>(acc, af, bfv);
    VMCNT8; FENCE; __builtin_amdgcn_s_barrier();
  }

  // drain in-flight wrap stages before reusing LDS as reduction scratch
  VMCNT0; FENCE;
  __builtin_amdgcn_s_barrier();

  // ---- epilogue: per-row sum(exp) over this 256-col tile + gt extraction ----
  float* red = (float*)&Abuf[0][0][0];
#pragma unroll
  for (int m = 0; m < 8; m++) {
#pragma unroll
    for (int j = 0; j < 4; j++) {
      const int rloc = wm * 128 + m * 16 + hi * 4 + j;
      const int gr = rowBase + rloc;
      const int te = teff[gr];
      float s = 0.f;
#pragma unroll
      for (int n = 0; n < 4; n++) {
        float v = acc[m][n][j];
        const int gc = colBase + wn * 64 + n * 16 + lo;
        if (te == gc) gt[gr] = v;
        s += __expf(v);
      }
#pragma unroll
      for (int d = 1; d < 16; d <<= 1) s += __shfl_xor(s, d);
      if (lo == 0) red[wn * 256 + rloc] = s;
    }
  }
  __syncthreads();
  if (tid < 256) {
    float S = red[tid] + red[256 + tid] + red[512 + tid] + red[768 + tid];
    partial[(size_t)(rowBase + tid) * NTN + by] = S;
  }
}

// ---- combine 125 tile partials per row -> per-token loss ----
__global__ void reduce_lse(const float* __restrict__ partial, const float* __restrict__ gt,
                           const int* __restrict__ ign, const float* __restrict__ divisor,
                           float* __restrict__ pertok) {
  int r = blockIdx.x * 4 + (threadIdx.x >> 6);
  int l = threadIdx.x & 63;
  float S = 0.f;
  for (int p = l; p < NTN; p += 64) S += partial[(size_t)r * NTN + p];
#pragma unroll
  for (int d = 1; d < 64; d <<= 1) S += __shfl_xor(S, d);
  if (l == 0) {
    float lse = __logf(S);
    pertok[r] = ign[r] ? 0.f : (lse - gt[r]) / divisor[0];
  }
}

// ---- deterministic final sum ----
__global__ void final_sum(const float* __restrict__ pertok, float* __restrict__ out) {
  __shared__ float red[16];
  float s = 0.f;
  for (int i = threadIdx.x; i < N_TOK; i += 1024) s += pertok[i];
#pragma unroll
  for (int d = 1; d < 64; d <<= 1) s += __shfl_xor(s, d);
  if ((threadIdx.x & 63) == 0) red[threadIdx.x >> 6] = s;
  __syncthreads();
  if (threadIdx.x == 0) {
    float t = 0.f;
    for (int i = 0; i < 16; i++) t += red[i];
    out[0] = t;
  }
}

extern "C" void kernel_launch(void* const* d_in, const int* in_sizes, int n_in,
                              void* d_out, int out_size, void* d_ws, size_t ws_size,
                              hipStream_t stream) {
  const float* x = (const float*)d_in[0];       // [4096,1024] f32
  const float* w = (const float*)d_in[1];       // [32000,1024] f32
  const int* targ = (const int*)d_in[2];        // [4096] int
  float* out = (float*)d_out;

  char* ws = (char*)d_ws;
  u16*   Xb      = (u16*)(ws);                     // 8,388,608 B
  u16*   Wb      = (u16*)(ws + 8388608);           // 65,536,000 B
  float* partial = (float*)(ws + 73924608);        // 2,048,000 B
  float* gt      = (float*)(ws + 75972608);        // 16,384 B
  int*   teff    = (int*)(ws + 75988992);          // 16,384 B
  int*   ign     = (int*)(ws + 76005376);          // 16,384 B
  float* divisor = (float*)(ws + 76021760);        // 256 B
  float* pertok  = (float*)(ws + 76022016);        // 16,384 B

  {
    int n8 = N_TOK * DIM / 8;
    cvt_bf16<<<(n8 + 255) / 256, 256, 0, stream>>>((const float4*)x, (u16x8*)Xb, n8);
  }
  {
    int n8 = NCLS * DIM / 8;
    cvt_bf16<<<(n8 + 255) / 256, 256, 0, stream>>>((const float4*)w, (u16x8*)Wb, n8);
  }
  prep_targ<<<1, 1024, 0, stream>>>(targ, teff, ign, divisor);

  gemm_lse<<<NTM * NTN, 512, 0, stream>>>(Xb, Wb, teff, gt, partial);  // 2000 blocks

  reduce_lse<<<N_TOK / 4, 256, 0, stream>>>(partial, gt, ign, divisor, pertok);
  final_sum<<<1, 1024, 0, stream>>>(pertok, out);
}

// Round 4
// 348.498 us; speedup vs baseline: 1.0835x; 1.0835x over previous
//
#include <hip/hip_runtime.h>
#include <stdint.h>

#define N_TOK 4096
#define DIM   1024
#define NCLS  32000
#define IGNIDX (-100)
#define BM 256
#define BN 256
#define BK 64
#define NTN (NCLS / BN)     // 125 col-tiles
#define NTM (N_TOK / BM)    // 16 row-tiles
#define KT  (DIM / BK)      // 16 K-tiles

typedef float  f32x4  __attribute__((ext_vector_type(4)));
typedef __bf16 bf16x8 __attribute__((ext_vector_type(8)));
typedef unsigned short u16;
typedef u16 u16x8 __attribute__((ext_vector_type(8)));

#define GLDS(g, s) __builtin_amdgcn_global_load_lds( \
    (__attribute__((address_space(1))) void*)(g),    \
    (__attribute__((address_space(3))) void*)(s), 16, 0, 0)
#define LGKM0 asm volatile("s_waitcnt lgkmcnt(0)" ::: "memory")
#define VMCNT8 asm volatile("s_waitcnt vmcnt(8)" ::: "memory")
#define VMCNT0 asm volatile("s_waitcnt vmcnt(0)" ::: "memory")
#define FENCE asm volatile("" ::: "memory")

__device__ __forceinline__ u16 f2bf(float f) {
  union { float f; uint32_t u; } c; c.f = f;
  uint32_t u = c.u;
  return (u16)((u + 0x7fffu + ((u >> 16) & 1u)) >> 16);  // RNE
}

// ---- fp32 -> bf16 bulk convert ----
__global__ void cvt_bf16(const float4* __restrict__ in, u16x8* __restrict__ out, int n8) {
  int i = blockIdx.x * 256 + threadIdx.x;
  if (i >= n8) return;
  float4 a = in[2 * i], b = in[2 * i + 1];
  u16x8 o;
  o[0] = f2bf(a.x); o[1] = f2bf(a.y); o[2] = f2bf(a.z); o[3] = f2bf(a.w);
  o[4] = f2bf(b.x); o[5] = f2bf(b.y); o[6] = f2bf(b.z); o[7] = f2bf(b.w);
  out[i] = o;
}

// ---- effective targets, ignore flags, divisor ----
__global__ void prep_targ(const int* __restrict__ targ, int* __restrict__ teff,
                          int* __restrict__ ign, float* __restrict__ divisor) {
  __shared__ int cnt[16];
  int local = 0;
  for (int i = threadIdx.x; i < N_TOK; i += 1024) {
    int t = targ[i];
    if (t != IGNIDX) local++;
    int pos = i & (N_TOK / 4 - 1);
    int te;
    if (pos < N_TOK / 4 - 1)      te = targ[i + 1];
    else if (i == N_TOK - 1)      te = IGNIDX;
    else                          te = targ[i + 2];
    ign[i] = (te == IGNIDX) ? 1 : 0;
    te = te < 0 ? 0 : (te > NCLS - 1 ? NCLS - 1 : te);
    teff[i] = te;
  }
#pragma unroll
  for (int d = 1; d < 64; d <<= 1) local += __shfl_xor(local, d);
  if ((threadIdx.x & 63) == 0) cnt[threadIdx.x >> 6] = local;
  __syncthreads();
  if (threadIdx.x == 0) {
    int t = 0;
    for (int i = 0; i < 16; i++) t += cnt[i];
    divisor[0] = (float)t;
  }
}

// stage 8 LDS rows starting at rb8 (multiple of 8): one gload_lds per thread.
// linear LDS dest; inverse-swizzled global source (slot s holds col-granule s^(r&7)).
__device__ __forceinline__ void stage8(const u16* srcTile, u16* ldsTile, int rb8, int l) {
  const int lr = l >> 3;
  const int lc = (l & 7) ^ lr;
  GLDS(srcTile + (size_t)(rb8 + lr) * DIM + lc * 8, ldsTile + (size_t)rb8 * BK);
}

template <int MH>  // A fragments for m-half MH (8 x ds_read_b128)
__device__ __forceinline__ void loadA(const u16* Ac, int wm, int lo, int hi, int key,
                                      bf16x8 (&aF)[4][2]) {
#pragma unroll
  for (int mm = 0; mm < 4; mm++) {
    const int r = wm * 128 + (MH * 4 + mm) * 16 + lo;
#pragma unroll
    for (int kk = 0; kk < 2; kk++)
      aF[mm][kk] = *(const bf16x8*)&Ac[(size_t)r * BK + ((((kk << 2) | hi)) ^ key) * 8];
  }
}

template <int NH>  // B fragments for n-half NH (4 x ds_read_b128)
__device__ __forceinline__ void loadB(const u16* Bc, int wn, int lo, int hi, int key,
                                      bf16x8 (&bF)[2][2]) {
#pragma unroll
  for (int nn = 0; nn < 2; nn++) {
    const int r = wn * 64 + (NH * 2 + nn) * 16 + lo;
#pragma unroll
    for (int kk = 0; kk < 2; kk++)
      bF[nn][kk] = *(const bf16x8*)&Bc[(size_t)r * BK + ((((kk << 2) | hi)) ^ key) * 8];
  }
}

template <int MH, int NH>
__device__ __forceinline__ void do_mfma(f32x4 (&acc)[8][4], const bf16x8 (&aF)[4][2],
                                        const bf16x8 (&bF)[2][2]) {
  __builtin_amdgcn_s_setprio(1);
#pragma unroll
  for (int mm = 0; mm < 4; mm++)
#pragma unroll
    for (int nn = 0; nn < 2; nn++)
#pragma unroll
      for (int kk = 0; kk < 2; kk++)
        acc[MH * 4 + mm][NH * 2 + nn] = __builtin_amdgcn_mfma_f32_16x16x32_bf16(
            aF[mm][kk], bF[nn][kk], acc[MH * 4 + mm][NH * 2 + nn], 0, 0, 0);
  __builtin_amdgcn_s_setprio(0);
}

// ---- fused 256x256 pipelined GEMM + per-tile sum(exp) partials ----
// Register-resident fragments: aF holds one m-half, bF0/bF1 hold the full
// K-tile B frags -> 24 ds_read_b128 per wave per K-tile (minimum), vs 48
// in the quadrant-reload schedule (round 3, LDS-pipe-bound at 12cyc/b128).
__launch_bounds__(512, 2)
__global__ void gemm_lse(const u16* __restrict__ Xb, const u16* __restrict__ Wb,
                         const int* __restrict__ teff, float* __restrict__ gt,
                         float* __restrict__ partial) {
  __shared__ u16 Abuf[2][BM][BK];   // 64 KiB
  __shared__ u16 Bbuf[2][BN][BK];   // 64 KiB

  const int tid = threadIdx.x;
  const int w = tid >> 6, l = tid & 63;
  const int wm = w >> 2, wn = w & 3;          // 2 x 4 wave grid
  const int hi = l >> 4, lo = l & 15;
  const int key = l & 7;
  const int w8 = w * 8;
  const int rb2 = (w >> 2) * 64 + (w & 3) * 8;   // S2 base rows (B n0-1 rows)
  const int rb3 = rb2 + 32;                      // S3 base rows (B n2-3 rows)

  // XCD-chunked bijective swizzle (2000 % 8 == 0)
  const int bid = blockIdx.x;
  const int wg = (bid & 7) * (NTM * NTN / 8) + (bid >> 3);
  const int bx = wg & (NTM - 1), by = wg >> 4;
  const int rowBase = bx * BM, colBase = by * BN;

  const u16* Asrc = Xb + (size_t)rowBase * DIM;
  const u16* Bsrc = Wb + (size_t)colBase * DIM;

  f32x4 acc[8][4] = {};

  u16* A0 = &Abuf[0][0][0]; u16* A1 = &Abuf[1][0][0];
  u16* B0 = &Bbuf[0][0][0]; u16* B1 = &Bbuf[1][0][0];

  // ---- prologue: seq = S0(0), S2(0), S3(0), S1(0), S0(1), S2(1) ----
  stage8(Asrc, A0, w8, l);            stage8(Asrc, A0, 128 + w8, l);        // S0(0)
  stage8(Bsrc, B0, rb2, l);           stage8(Bsrc, B0, rb2 + 128, l);       // S2(0)
  stage8(Bsrc, B0, rb3, l);           stage8(Bsrc, B0, rb3 + 128, l);       // S3(0)
  stage8(Asrc, A0, 64 + w8, l);       stage8(Asrc, A0, 192 + w8, l);        // S1(0)
  stage8(Asrc + BK, A1, w8, l);       stage8(Asrc + BK, A1, 128 + w8, l);   // S0(1)
  stage8(Bsrc + BK, B1, rb2, l);      stage8(Bsrc + BK, B1, rb2 + 128, l);  // S2(1)
  VMCNT8;  // oldest 4 loads (S0(0), S2(0)) complete
  FENCE;
  __builtin_amdgcn_s_barrier();

  for (int t = 0; t < KT; t++) {
    const int cur = t & 1;
    const u16* Ac = cur ? A1 : A0;  const u16* Bc = cur ? B1 : B0;
    u16* An = cur ? A0 : A1;        u16* Bn = cur ? B0 : B1;
    u16* Acw = cur ? A1 : A0;       u16* Bcw = cur ? B1 : B0;
    const int t1 = (t + 1) & (KT - 1);
    const int t2 = (t + 2) & (KT - 1);
    const u16* As1 = Asrc + t1 * BK; const u16* Bs1 = Bsrc + t1 * BK;
    const u16* As2 = Asrc + t2 * BK; const u16* Bs2 = Bsrc + t2 * BK;

    bf16x8 aF[4][2], bF0[2][2], bF1[2][2];

    // ---- p0: load A-half0 (S0) + B n0-1 (S2); issue S3(t+1) -> other buf ----
    loadA<0>(Ac, wm, lo, hi, key, aF);
    loadB<0>(Bc, wn, lo, hi, key, bF0);
    stage8(Bs1, Bn, rb3, l); stage8(Bs1, Bn, rb3 + 128, l);
    FENCE; __builtin_amdgcn_s_barrier();
    LGKM0; __builtin_amdgcn_sched_barrier(0);
    do_mfma<0, 0>(acc, aF, bF0);
    VMCNT8; FENCE; __builtin_amdgcn_s_barrier();

    // ---- p1: load B n2-3 (S3); issue S1(t+1) -> other buf ----
    loadB<1>(Bc, wn, lo, hi, key, bF1);
    stage8(As1, An, 64 + w8, l); stage8(As1, An, 192 + w8, l);
    FENCE; __builtin_amdgcn_s_barrier();
    LGKM0; __builtin_amdgcn_sched_barrier(0);
    do_mfma<0, 1>(acc, aF, bF1);
    VMCNT8; FENCE; __builtin_amdgcn_s_barrier();

    // ---- p2: load A-half1 (S1); issue S0(t+2) -> CURRENT buf (S0 free after p0) ----
    loadA<1>(Ac, wm, lo, hi, key, aF);
    stage8(As2, Acw, w8, l); stage8(As2, Acw, 128 + w8, l);
    FENCE; __builtin_amdgcn_s_barrier();
    LGKM0; __builtin_amdgcn_sched_barrier(0);
    do_mfma<1, 0>(acc, aF, bF0);          // reuse bF0 from p0
    FENCE; __builtin_amdgcn_s_barrier();  // no vmcnt here

    // ---- p3: no ds loads; issue S2(t+2) -> CURRENT buf (S2 free after p0) ----
    stage8(Bs2, Bcw, rb2, l); stage8(Bs2, Bcw, rb2 + 128, l);
    FENCE; __builtin_amdgcn_s_barrier();
    do_mfma<1, 1>(acc, aF, bF1);          // reuse bF1 from p1
    VMCNT8; FENCE; __builtin_amdgcn_s_barrier();
  }

  // drain in-flight wrap stages before reusing LDS as reduction scratch
  VMCNT0; FENCE;
  __builtin_amdgcn_s_barrier();

  // ---- epilogue: per-row sum(exp) over this 256-col tile + gt extraction ----
  float* red = (float*)&Abuf[0][0][0];
#pragma unroll
  for (int m = 0; m < 8; m++) {
#pragma unroll
    for (int j = 0; j < 4; j++) {
      const int rloc = wm * 128 + m * 16 + hi * 4 + j;
      const int gr = rowBase + rloc;
      const int te = teff[gr];
      float s = 0.f;
#pragma unroll
      for (int n = 0; n < 4; n++) {
        float v = acc[m][n][j];
        const int gc = colBase + wn * 64 + n * 16 + lo;
        if (te == gc) gt[gr] = v;
        s += __expf(v);
      }
#pragma unroll
      for (int d = 1; d < 16; d <<= 1) s += __shfl_xor(s, d);
      if (lo == 0) red[wn * 256 + rloc] = s;
    }
  }
  __syncthreads();
  if (tid < 256) {
    float S = red[tid] + red[256 + tid] + red[512 + tid] + red[768 + tid];
    partial[(size_t)(rowBase + tid) * NTN + by] = S;
  }
}

// ---- combine 125 tile partials per row -> per-token loss ----
__global__ void reduce_lse(const float* __restrict__ partial, const float* __restrict__ gt,
                           const int* __restrict__ ign, const float* __restrict__ divisor,
                           float* __restrict__ pertok) {
  int r = blockIdx.x * 4 + (threadIdx.x >> 6);
  int l = threadIdx.x & 63;
  float S = 0.f;
  for (int p = l; p < NTN; p += 64) S += partial[(size_t)r * NTN + p];
#pragma unroll
  for (int d = 1; d < 64; d <<= 1) S += __shfl_xor(S, d);
  if (l == 0) {
    float lse = __logf(S);
    pertok[r] = ign[r] ? 0.f : (lse - gt[r]) / divisor[0];
  }
}

// ---- deterministic final sum ----
__global__ void final_sum(const float* __restrict__ pertok, float* __restrict__ out) {
  __shared__ float red[16];
  float s = 0.f;
  for (int i = threadIdx.x; i < N_TOK; i += 1024) s += pertok[i];
#pragma unroll
  for (int d = 1; d < 64; d <<= 1) s += __shfl_xor(s, d);
  if ((threadIdx.x & 63) == 0) red[threadIdx.x >> 6] = s;
  __syncthreads();
  if (threadIdx.x == 0) {
    float t = 0.f;
    for (int i = 0; i < 16; i++) t += red[i];
    out[0] = t;
  }
}

extern "C" void kernel_launch(void* const* d_in, const int* in_sizes, int n_in,
                              void* d_out, int out_size, void* d_ws, size_t ws_size,
                              hipStream_t stream) {
  const float* x = (const float*)d_in[0];       // [4096,1024] f32
  const float* w = (const float*)d_in[1];       // [32000,1024] f32
  const int* targ = (const int*)d_in[2];        // [4096] int
  float* out = (float*)d_out;

  char* ws = (char*)d_ws;
  u16*   Xb      = (u16*)(ws);                     // 8,388,608 B
  u16*   Wb      = (u16*)(ws + 8388608);           // 65,536,000 B
  float* partial = (float*)(ws + 73924608);        // 2,048,000 B
  float* gt      = (float*)(ws + 75972608);        // 16,384 B
  int*   teff    = (int*)(ws + 75988992);          // 16,384 B
  int*   ign     = (int*)(ws + 76005376);          // 16,384 B
  float* divisor = (float*)(ws + 76021760);        // 256 B
  float* pertok  = (float*)(ws + 76022016);        // 16,384 B

  {
    int n8 = N_TOK * DIM / 8;
    cvt_bf16<<<(n8 + 255) / 256, 256, 0, stream>>>((const float4*)x, (u16x8*)Xb, n8);
  }
  {
    int n8 = NCLS * DIM / 8;
    cvt_bf16<<<(n8 + 255) / 256, 256, 0, stream>>>((const float4*)w, (u16x8*)Wb, n8);
  }
  prep_targ<<<1, 1024, 0, stream>>>(targ, teff, ign, divisor);

  gemm_lse<<<NTM * NTN, 512, 0, stream>>>(Xb, Wb, teff, gt, partial);  // 2000 blocks

  reduce_lse<<<N_TOK / 4, 256, 0, stream>>>(partial, gt, ign, divisor, pertok);
  final_sum<<<1, 1024, 0, stream>>>(pertok, out);
}

// Round 5
// 344.594 us; speedup vs baseline: 1.0957x; 1.0113x over previous
//
#include <hip/hip_runtime.h>
#include <stdint.h>

#define N_TOK 4096
#define DIM   1024
#define NCLS  32000
#define IGNIDX (-100)
#define BM 256
#define BN 256
#define BK 64
#define NTN (NCLS / BN)     // 125 col-tiles
#define NTM (N_TOK / BM)    // 16 row-tiles
#define KT  (DIM / BK)      // 16 K-tiles

typedef float  f32x4  __attribute__((ext_vector_type(4)));
typedef __bf16 bf16x8 __attribute__((ext_vector_type(8)));
typedef unsigned short u16;
typedef u16 u16x8 __attribute__((ext_vector_type(8)));

#define GLDS(g, s) __builtin_amdgcn_global_load_lds( \
    (__attribute__((address_space(1))) void*)(g),    \
    (__attribute__((address_space(3))) void*)(s), 16, 0, 0)
#define LGKM0 asm volatile("s_waitcnt lgkmcnt(0)" ::: "memory")
#define VMCNT8 asm volatile("s_waitcnt vmcnt(8)" ::: "memory")
#define VMCNT6 asm volatile("s_waitcnt vmcnt(6)" ::: "memory")
#define VMCNT0 asm volatile("s_waitcnt vmcnt(0)" ::: "memory")
#define FENCE asm volatile("" ::: "memory")

__device__ __forceinline__ u16 f2bf(float f) {
  union { float f; uint32_t u; } c; c.f = f;
  uint32_t u = c.u;
  return (u16)((u + 0x7fffu + ((u >> 16) & 1u)) >> 16);  // RNE
}

// ---- fp32 -> bf16 bulk convert ----
__global__ void cvt_bf16(const float4* __restrict__ in, u16x8* __restrict__ out, int n8) {
  int i = blockIdx.x * 256 + threadIdx.x;
  if (i >= n8) return;
  float4 a = in[2 * i], b = in[2 * i + 1];
  u16x8 o;
  o[0] = f2bf(a.x); o[1] = f2bf(a.y); o[2] = f2bf(a.z); o[3] = f2bf(a.w);
  o[4] = f2bf(b.x); o[5] = f2bf(b.y); o[6] = f2bf(b.z); o[7] = f2bf(b.w);
  out[i] = o;
}

// ---- effective targets, ignore flags, divisor ----
__global__ void prep_targ(const int* __restrict__ targ, int* __restrict__ teff,
                          int* __restrict__ ign, float* __restrict__ divisor) {
  __shared__ int cnt[16];
  int local = 0;
  for (int i = threadIdx.x; i < N_TOK; i += 1024) {
    int t = targ[i];
    if (t != IGNIDX) local++;
    int pos = i & (N_TOK / 4 - 1);
    int te;
    if (pos < N_TOK / 4 - 1)      te = targ[i + 1];
    else if (i == N_TOK - 1)      te = IGNIDX;
    else                          te = targ[i + 2];
    ign[i] = (te == IGNIDX) ? 1 : 0;
    te = te < 0 ? 0 : (te > NCLS - 1 ? NCLS - 1 : te);
    teff[i] = te;
  }
#pragma unroll
  for (int d = 1; d < 64; d <<= 1) local += __shfl_xor(local, d);
  if ((threadIdx.x & 63) == 0) cnt[threadIdx.x >> 6] = local;
  __syncthreads();
  if (threadIdx.x == 0) {
    int t = 0;
    for (int i = 0; i < 16; i++) t += cnt[i];
    divisor[0] = (float)t;
  }
}

// stage 8 LDS rows starting at rb8 (multiple of 8): one gload_lds per thread.
// linear LDS dest; inverse-swizzled global source (slot s holds col-granule s^(r&7)).
__device__ __forceinline__ void stage8(const u16* srcTile, u16* ldsTile, int rb8, int l) {
  const int lr = l >> 3;
  const int lc = (l & 7) ^ lr;
  GLDS(srcTile + (size_t)(rb8 + lr) * DIM + lc * 8, ldsTile + (size_t)rb8 * BK);
}

template <int MH>  // A fragments for m-half MH (8 x ds_read_b128)
__device__ __forceinline__ void loadA(const u16* Ac, int wm, int lo, int hi, int key,
                                      bf16x8 (&aF)[4][2]) {
#pragma unroll
  for (int mm = 0; mm < 4; mm++) {
    const int r = wm * 128 + (MH * 4 + mm) * 16 + lo;
#pragma unroll
    for (int kk = 0; kk < 2; kk++)
      aF[mm][kk] = *(const bf16x8*)&Ac[(size_t)r * BK + ((((kk << 2) | hi)) ^ key) * 8];
  }
}

template <int NH>  // B fragments for n-half NH (4 x ds_read_b128)
__device__ __forceinline__ void loadB(const u16* Bc, int wn, int lo, int hi, int key,
                                      bf16x8 (&bF)[2][2]) {
#pragma unroll
  for (int nn = 0; nn < 2; nn++) {
    const int r = wn * 64 + (NH * 2 + nn) * 16 + lo;
#pragma unroll
    for (int kk = 0; kk < 2; kk++)
      bF[nn][kk] = *(const bf16x8*)&Bc[(size_t)r * BK + ((((kk << 2) | hi)) ^ key) * 8];
  }
}

template <int MH, int NH>
__device__ __forceinline__ void do_mfma(f32x4 (&acc)[8][4], const bf16x8 (&aF)[4][2],
                                        const bf16x8 (&bF)[2][2]) {
  __builtin_amdgcn_s_setprio(1);
#pragma unroll
  for (int mm = 0; mm < 4; mm++)
#pragma unroll
    for (int nn = 0; nn < 2; nn++)
#pragma unroll
      for (int kk = 0; kk < 2; kk++)
        acc[MH * 4 + mm][NH * 2 + nn] = __builtin_amdgcn_mfma_f32_16x16x32_bf16(
            aF[mm][kk], bF[nn][kk], acc[MH * 4 + mm][NH * 2 + nn], 0, 0, 0);
  __builtin_amdgcn_s_setprio(0);
}

// ---- fused 256x256 pipelined GEMM + per-tile sum(exp) partials ----
// Balanced 8/4/8/4 ds_read phases: bF0 for tile t is pre-loaded at p3 of
// tile t-1 (loop-carried registers), so no phase exceeds an 8-read burst
// before its lgkmcnt(0). Uniform vmcnt(6) per phase: a region staged at
// phase F is complete by end of F+3; all consumers read at distance >= 3.
__launch_bounds__(512, 2)
__global__ void gemm_lse(const u16* __restrict__ Xb, const u16* __restrict__ Wb,
                         const int* __restrict__ teff, float* __restrict__ gt,
                         float* __restrict__ partial) {
  __shared__ u16 Abuf[2][BM][BK];   // 64 KiB
  __shared__ u16 Bbuf[2][BN][BK];   // 64 KiB

  const int tid = threadIdx.x;
  const int w = tid >> 6, l = tid & 63;
  const int wm = w >> 2, wn = w & 3;          // 2 x 4 wave grid
  const int hi = l >> 4, lo = l & 15;
  const int key = l & 7;
  const int w8 = w * 8;
  const int rb2 = (w >> 2) * 64 + (w & 3) * 8;   // S2 base rows (B n0-1 rows)
  const int rb3 = rb2 + 32;                      // S3 base rows (B n2-3 rows)

  // XCD-chunked bijective swizzle (2000 % 8 == 0)
  const int bid = blockIdx.x;
  const int wg = (bid & 7) * (NTM * NTN / 8) + (bid >> 3);
  const int bx = wg & (NTM - 1), by = wg >> 4;
  const int rowBase = bx * BM, colBase = by * BN;

  const u16* Asrc = Xb + (size_t)rowBase * DIM;
  const u16* Bsrc = Wb + (size_t)colBase * DIM;

  f32x4 acc[8][4] = {};

  u16* A0 = &Abuf[0][0][0]; u16* A1 = &Abuf[1][0][0];
  u16* B0 = &Bbuf[0][0][0]; u16* B1 = &Bbuf[1][0][0];

  // ---- prologue: seq = S0(0), S2(0), S3(0), S1(0), S0(1), S2(1) ----
  stage8(Asrc, A0, w8, l);            stage8(Asrc, A0, 128 + w8, l);        // S0(0)
  stage8(Bsrc, B0, rb2, l);           stage8(Bsrc, B0, rb2 + 128, l);       // S2(0)
  stage8(Bsrc, B0, rb3, l);           stage8(Bsrc, B0, rb3 + 128, l);       // S3(0)
  stage8(Asrc, A0, 64 + w8, l);       stage8(Asrc, A0, 192 + w8, l);        // S1(0)
  stage8(Asrc + BK, A1, w8, l);       stage8(Asrc + BK, A1, 128 + w8, l);   // S0(1)
  stage8(Bsrc + BK, B1, rb2, l);      stage8(Bsrc + BK, B1, rb2 + 128, l);  // S2(1)
  VMCNT8;  // oldest 4 loads (S0(0), S2(0)) complete
  FENCE;
  __builtin_amdgcn_s_barrier();

  bf16x8 aF[4][2], bF0[2][2], bF1[2][2];
  // pre-load bF0 for tile 0 (from S2(0), just drained)
  loadB<0>(B0, wn, lo, hi, key, bF0);

  for (int t = 0; t < KT; t++) {
    const int cur = t & 1;
    const u16* Ac = cur ? A1 : A0;  const u16* Bc = cur ? B1 : B0;
    u16* An = cur ? A0 : A1;        u16* Bn = cur ? B0 : B1;
    const u16* Bnr = cur ? B0 : B1;            // next-tile B (read at p3)
    u16* Acw = cur ? A1 : A0;       u16* Bcw = cur ? B1 : B0;
    const int t1 = (t + 1) & (KT - 1);
    const int t2 = (t + 2) & (KT - 1);
    const u16* As1 = Asrc + t1 * BK; const u16* Bs1 = Bsrc + t1 * BK;
    const u16* As2 = Asrc + t2 * BK; const u16* Bs2 = Bsrc + t2 * BK;

    // ---- p0: load A-half0 (8); MFMA q(0,0) w/ carried bF0; issue S3(t+1)->other ----
    loadA<0>(Ac, wm, lo, hi, key, aF);
    stage8(Bs1, Bn, rb3, l); stage8(Bs1, Bn, rb3 + 128, l);
    FENCE; __builtin_amdgcn_s_barrier();
    LGKM0; __builtin_amdgcn_sched_barrier(0);
    do_mfma<0, 0>(acc, aF, bF0);
    VMCNT6; FENCE; __builtin_amdgcn_s_barrier();

    // ---- p1: load B n2-3 (4); MFMA q(0,1); issue S1(t+1)->other ----
    loadB<1>(Bc, wn, lo, hi, key, bF1);
    stage8(As1, An, 64 + w8, l); stage8(As1, An, 192 + w8, l);
    FENCE; __builtin_amdgcn_s_barrier();
    LGKM0; __builtin_amdgcn_sched_barrier(0);
    do_mfma<0, 1>(acc, aF, bF1);
    VMCNT6; FENCE; __builtin_amdgcn_s_barrier();

    // ---- p2: load A-half1 (8); MFMA q(1,0) w/ bF0; issue S0(t+2)->CURRENT ----
    loadA<1>(Ac, wm, lo, hi, key, aF);
    stage8(As2, Acw, w8, l); stage8(As2, Acw, 128 + w8, l);
    FENCE; __builtin_amdgcn_s_barrier();
    LGKM0; __builtin_amdgcn_sched_barrier(0);
    do_mfma<1, 0>(acc, aF, bF0);
    VMCNT6; FENCE; __builtin_amdgcn_s_barrier();

    // ---- p3: pre-load bF0 for tile t+1 from OTHER buf (4); MFMA q(1,1); issue S2(t+2)->CURRENT ----
    loadB<0>(Bnr, wn, lo, hi, key, bF0);
    stage8(Bs2, Bcw, rb2, l); stage8(Bs2, Bcw, rb2 + 128, l);
    FENCE; __builtin_amdgcn_s_barrier();
    LGKM0; __builtin_amdgcn_sched_barrier(0);
    do_mfma<1, 1>(acc, aF, bF1);
    VMCNT6; FENCE; __builtin_amdgcn_s_barrier();
  }

  // drain in-flight wrap stages before reusing LDS as reduction scratch
  VMCNT0; FENCE;
  __builtin_amdgcn_s_barrier();

  // ---- epilogue: per-row sum(exp) over this 256-col tile + gt extraction ----
  float* red = (float*)&Abuf[0][0][0];
#pragma unroll
  for (int m = 0; m < 8; m++) {
#pragma unroll
    for (int j = 0; j < 4; j++) {
      const int rloc = wm * 128 + m * 16 + hi * 4 + j;
      const int gr = rowBase + rloc;
      const int te = teff[gr];
      float s = 0.f;
#pragma unroll
      for (int n = 0; n < 4; n++) {
        float v = acc[m][n][j];
        const int gc = colBase + wn * 64 + n * 16 + lo;
        if (te == gc) gt[gr] = v;
        s += __expf(v);
      }
#pragma unroll
      for (int d = 1; d < 16; d <<= 1) s += __shfl_xor(s, d);
      if (lo == 0) red[wn * 256 + rloc] = s;
    }
  }
  __syncthreads();
  if (tid < 256) {
    float S = red[tid] + red[256 + tid] + red[512 + tid] + red[768 + tid];
    partial[(size_t)(rowBase + tid) * NTN + by] = S;
  }
}

// ---- combine 125 tile partials per row -> per-token loss ----
__global__ void reduce_lse(const float* __restrict__ partial, const float* __restrict__ gt,
                           const int* __restrict__ ign, const float* __restrict__ divisor,
                           float* __restrict__ pertok) {
  int r = blockIdx.x * 4 + (threadIdx.x >> 6);
  int l = threadIdx.x & 63;
  float S = 0.f;
  for (int p = l; p < NTN; p += 64) S += partial[(size_t)r * NTN + p];
#pragma unroll
  for (int d = 1; d < 64; d <<= 1) S += __shfl_xor(S, d);
  if (l == 0) {
    float lse = __logf(S);
    pertok[r] = ign[r] ? 0.f : (lse - gt[r]) / divisor[0];
  }
}

// ---- deterministic final sum ----
__global__ void final_sum(const float* __restrict__ pertok, float* __restrict__ out) {
  __shared__ float red[16];
  float s = 0.f;
  for (int i = threadIdx.x; i < N_TOK; i += 1024) s += pertok[i];
#pragma unroll
  for (int d = 1; d < 64; d <<= 1) s += __shfl_xor(s, d);
  if ((threadIdx.x & 63) == 0) red[threadIdx.x >> 6] = s;
  __syncthreads();
  if (threadIdx.x == 0) {
    float t = 0.f;
    for (int i = 0; i < 16; i++) t += red[i];
    out[0] = t;
  }
}

extern "C" void kernel_launch(void* const* d_in, const int* in_sizes, int n_in,
                              void* d_out, int out_size, void* d_ws, size_t ws_size,
                              hipStream_t stream) {
  const float* x = (const float*)d_in[0];       // [4096,1024] f32
  const float* w = (const float*)d_in[1];       // [32000,1024] f32
  const int* targ = (const int*)d_in[2];        // [4096] int
  float* out = (float*)d_out;

  char* ws = (char*)d_ws;
  u16*   Xb      = (u16*)(ws);                     // 8,388,608 B
  u16*   Wb      = (u16*)(ws + 8388608);           // 65,536,000 B
  float* partial = (float*)(ws + 73924608);        // 2,048,000 B
  float* gt      = (float*)(ws + 75972608);        // 16,384 B
  int*   teff    = (int*)(ws + 75988992);          // 16,384 B
  int*   ign     = (int*)(ws + 76005376);          // 16,384 B
  float* divisor = (float*)(ws + 76021760);        // 256 B
  float* pertok  = (float*)(ws + 76022016);        // 16,384 B

  {
    int n8 = N_TOK * DIM / 8;
    cvt_bf16<<<(n8 + 255) / 256, 256, 0, stream>>>((const float4*)x, (u16x8*)Xb, n8);
  }
  {
    int n8 = NCLS * DIM / 8;
    cvt_bf16<<<(n8 + 255) / 256, 256, 0, stream>>>((const float4*)w, (u16x8*)Wb, n8);
  }
  prep_targ<<<1, 1024, 0, stream>>>(targ, teff, ign, divisor);

  gemm_lse<<<NTM * NTN, 512, 0, stream>>>(Xb, Wb, teff, gt, partial);  // 2000 blocks

  reduce_lse<<<N_TOK / 4, 256, 0, stream>>>(partial, gt, ign, divisor, pertok);
  final_sum<<<1, 1024, 0, stream>>>(pertok, out);
}

// Round 7
// 238.531 us; speedup vs baseline: 1.5829x; 1.4447x over previous
//
#include <hip/hip_runtime.h>
#include <stdint.h>

#define N_TOK 4096
#define DIM   1024          // K elements = K bytes in fp8
#define NCLS  32000
#define IGNIDX (-100)
#define BM 256
#define BN 256
#define BKB 128             // fp8 K-bytes per tile
#define NTN (NCLS / BN)     // 125 col-tiles
#define NTM (N_TOK / BM)    // 16 row-tiles
#define KT  (DIM / BKB)     // 8 K-tiles

typedef float   f32x4 __attribute__((ext_vector_type(4)));
typedef int     i32x4 __attribute__((ext_vector_type(4)));
typedef int     i32x8 __attribute__((ext_vector_type(8)));
typedef uint8_t u8;

#define GLDS(g, s) __builtin_amdgcn_global_load_lds( \
    (__attribute__((address_space(1))) void*)(g),    \
    (__attribute__((address_space(3))) void*)(s), 16, 0, 0)
#define LGKM0 asm volatile("s_waitcnt lgkmcnt(0)" ::: "memory")
#define VMCNT6 asm volatile("s_waitcnt vmcnt(6)" ::: "memory")
#define VMCNT4 asm volatile("s_waitcnt vmcnt(4)" ::: "memory")
#define VMCNT0 asm volatile("s_waitcnt vmcnt(0)" ::: "memory")
#define FENCE asm volatile("" ::: "memory")

#define SCALE_ONE 0x7F7F7F7F   // e8m0 2^0 in every byte -> immune to byte-select

// ---- fp32 -> fp8 e4m3 bulk convert (8 elems/thread) ----
__global__ void cvt_fp8(const float4* __restrict__ in, uint2* __restrict__ out, int n8) {
  int i = blockIdx.x * 256 + threadIdx.x;
  if (i >= n8) return;
  float4 a = in[2 * i], b = in[2 * i + 1];
  int lo = 0, hi = 0;
  lo = __builtin_amdgcn_cvt_pk_fp8_f32(a.x, a.y, lo, false);
  lo = __builtin_amdgcn_cvt_pk_fp8_f32(a.z, a.w, lo, true);
  hi = __builtin_amdgcn_cvt_pk_fp8_f32(b.x, b.y, hi, false);
  hi = __builtin_amdgcn_cvt_pk_fp8_f32(b.z, b.w, hi, true);
  out[i] = make_uint2((unsigned)lo, (unsigned)hi);
}

// ---- effective targets, ignore flags, divisor ----
__global__ void prep_targ(const int* __restrict__ targ, int* __restrict__ teff,
                          int* __restrict__ ign, float* __restrict__ divisor) {
  __shared__ int cnt[16];
  int local = 0;
  for (int i = threadIdx.x; i < N_TOK; i += 1024) {
    int t = targ[i];
    if (t != IGNIDX) local++;
    int pos = i & (N_TOK / 4 - 1);
    int te;
    if (pos < N_TOK / 4 - 1)      te = targ[i + 1];
    else if (i == N_TOK - 1)      te = IGNIDX;
    else                          te = targ[i + 2];
    ign[i] = (te == IGNIDX) ? 1 : 0;
    te = te < 0 ? 0 : (te > NCLS - 1 ? NCLS - 1 : te);
    teff[i] = te;
  }
#pragma unroll
  for (int d = 1; d < 64; d <<= 1) local += __shfl_xor(local, d);
  if ((threadIdx.x & 63) == 0) cnt[threadIdx.x >> 6] = local;
  __syncthreads();
  if (threadIdx.x == 0) {
    int t = 0;
    for (int i = 0; i < 16; i++) t += cnt[i];
    divisor[0] = (float)t;
  }
}

// ---- staging: linear LDS dest, inverse-swizzled global source ----
// physical 16B slot s of row r holds logical K-granule s ^ (r&7).

// A: rows [rb, rb+64), wave w covers rb + w*8 ..+8
__device__ __forceinline__ void stageA(const u8* src, u8* lds, int rb, int w, int l) {
  const int row = rb + w * 8 + (l >> 3);
  const int g = (l & 7) ^ (l >> 3);
  GLDS(src + (size_t)row * DIM + g * 16, lds + (size_t)(rb + w * 8) * BKB);
}
// B half h (rows band*64 + h*32 ..+32), call c covers bands {2c, 2c+1}
__device__ __forceinline__ void stageB(const u8* src, u8* lds, int h, int c, int w, int l) {
  const int rb = (c * 2 + (w >> 2)) * 64 + h * 32 + (w & 3) * 8;
  const int row = rb + (l >> 3);
  const int g = (l & 7) ^ (l >> 3);
  GLDS(src + (size_t)row * DIM + g * 16, lds + (size_t)rb * BKB);
}

// read one 16x16x128 fragment: lane holds 32 K-bytes (2 x b128)
__device__ __forceinline__ i32x8 read_frag(const u8* buf, int r, int g0, int q) {
  const i32x4 a = *(const i32x4*)(buf + (size_t)r * BKB + ((g0 ^ q) << 4));
  const i32x4 b = *(const i32x4*)(buf + (size_t)r * BKB + (((g0 + 1) ^ q) << 4));
  i32x8 o;
  o[0] = a[0]; o[1] = a[1]; o[2] = a[2]; o[3] = a[3];
  o[4] = b[0]; o[5] = b[1]; o[6] = b[2]; o[7] = b[3];
  return o;
}

template <int MH>  // A fragments for m-half MH (8 x ds_read_b128)
__device__ __forceinline__ void loadA(const u8* Ac, int wm, int lo, int g0, int q,
                                      i32x8 (&aF)[4]) {
#pragma unroll
  for (int mm = 0; mm < 4; mm++)
    aF[mm] = read_frag(Ac, wm * 128 + (MH * 4 + mm) * 16 + lo, g0, q);
}
template <int NH>  // B fragments for n-half NH (4 x ds_read_b128)
__device__ __forceinline__ void loadB(const u8* Bc, int wn, int lo, int g0, int q,
                                      i32x8 (&bF)[2]) {
#pragma unroll
  for (int nn = 0; nn < 2; nn++)
    bF[nn] = read_frag(Bc, wn * 64 + (NH * 2 + nn) * 16 + lo, g0, q);
}

template <int MH, int NH>
__device__ __forceinline__ void do_mfma(f32x4 (&acc)[8][4], const i32x8 (&aF)[4],
                                        const i32x8 (&bF)[2]) {
  __builtin_amdgcn_s_setprio(1);
#pragma unroll
  for (int mm = 0; mm < 4; mm++)
#pragma unroll
    for (int nn = 0; nn < 2; nn++)
      acc[MH * 4 + mm][NH * 2 + nn] = __builtin_amdgcn_mfma_scale_f32_16x16x128_f8f6f4(
          aF[mm], bF[nn], acc[MH * 4 + mm][NH * 2 + nn],
          0, 0,                 // cbsz = fp8(A), blgp = fp8(B)
          0, SCALE_ONE,         // A scale: 2^0 (all bytes identical)
          0, SCALE_ONE);        // B scale: 2^0
  __builtin_amdgcn_s_setprio(0);
}

// ---- fused 256x256 MX-fp8 pipelined GEMM + per-tile sum(exp) partials ----
__launch_bounds__(512, 2)
__global__ void gemm_lse(const u8* __restrict__ Xf8, const u8* __restrict__ Wf8,
                         const int* __restrict__ teff, float* __restrict__ gt,
                         float* __restrict__ partial) {
  __shared__ __align__(16) u8 Abuf[2][BM][BKB];   // 64 KiB
  __shared__ __align__(16) u8 Bbuf[2][BN][BKB];   // 64 KiB

  const int tid = threadIdx.x;
  const int w = tid >> 6, l = tid & 63;
  const int wm = w >> 2, wn = w & 3;          // 2 x 4 wave grid
  const int hi = l >> 4, lo = l & 15;
  const int g0 = hi * 2;                      // K-granule base for frag reads
  const int q = l & 7;                        // row&7 of frag rows

  // XCD-chunked bijective swizzle (2000 % 8 == 0)
  const int bid = blockIdx.x;
  const int wg = (bid & 7) * (NTM * NTN / 8) + (bid >> 3);
  const int bx = wg & (NTM - 1), by = wg >> 4;
  const int rowBase = bx * BM, colBase = by * BN;

  const u8* Asrc = Xf8 + (size_t)rowBase * DIM;
  const u8* Bsrc = Wf8 + (size_t)colBase * DIM;

  f32x4 acc[8][4] = {};

  u8* A0 = &Abuf[0][0][0]; u8* A1 = &Abuf[1][0][0];
  u8* B0 = &Bbuf[0][0][0]; u8* B1 = &Bbuf[1][0][0];

  // ---- prologue: Ah0(0), Bh0(0), Ah1(0), Bh1(0), Ah0(1), Bh0(1) = 12 calls ----
  // (round-6 bug: Ah0(1) was missing -> tile-1 read uninitialized LDS -> fp8-NaN bytes)
  stageA(Asrc, A0, 0, w, l);          stageA(Asrc, A0, 128, w, l);          // Ah0(0)
  stageB(Bsrc, B0, 0, 0, w, l);       stageB(Bsrc, B0, 0, 1, w, l);         // Bh0(0)
  stageA(Asrc, A0, 64, w, l);         stageA(Asrc, A0, 192, w, l);          // Ah1(0)
  stageB(Bsrc, B0, 1, 0, w, l);       stageB(Bsrc, B0, 1, 1, w, l);         // Bh1(0)
  stageA(Asrc + BKB, A1, 0, w, l);    stageA(Asrc + BKB, A1, 128, w, l);    // Ah0(1)
  stageB(Bsrc + BKB, B1, 0, 0, w, l); stageB(Bsrc + BKB, B1, 0, 1, w, l);   // Bh0(1)
  VMCNT4;  // all tile-0 regions complete; Ah0(1)/Bh0(1) may linger
  FENCE;
  __builtin_amdgcn_s_barrier();

  i32x8 aF[4], bF0[2], bF1[2];
  loadB<0>(B0, wn, lo, g0, q, bF0);   // preload bF0 for tile 0

  for (int t = 0; t < KT; t++) {
    const int cur = t & 1;
    const u8* Ac = cur ? A1 : A0;  const u8* Bc = cur ? B1 : B0;
    u8* An = cur ? A0 : A1;        u8* Bn = cur ? B0 : B1;
    const u8* Bnr = cur ? B0 : B1;             // next-tile B (preload at p3)
    u8* Acw = cur ? A1 : A0;       u8* Bcw = cur ? B1 : B0;
    const int t1 = (t + 1) & (KT - 1);
    const int t2 = (t + 2) & (KT - 1);
    const u8* As1 = Asrc + t1 * BKB; const u8* Bs1 = Bsrc + t1 * BKB;
    const u8* As2 = Asrc + t2 * BKB; const u8* Bs2 = Bsrc + t2 * BKB;

    // ---- p0: loadA half0 (8); q(0,0) w/ carried bF0; stage Bh1(t+1)->other ----
    loadA<0>(Ac, wm, lo, g0, q, aF);
    stageB(Bs1, Bn, 1, 0, w, l); stageB(Bs1, Bn, 1, 1, w, l);
    FENCE; __builtin_amdgcn_s_barrier();
    LGKM0; __builtin_amdgcn_sched_barrier(0);
    do_mfma<0, 0>(acc, aF, bF0);
    VMCNT6; FENCE; __builtin_amdgcn_s_barrier();

    // ---- p1: loadB half1 (4); q(0,1); stage Ah1(t+1)->other ----
    loadB<1>(Bc, wn, lo, g0, q, bF1);
    stageA(As1, An, 64, w, l); stageA(As1, An, 192, w, l);
    FENCE; __builtin_amdgcn_s_barrier();
    LGKM0; __builtin_amdgcn_sched_barrier(0);
    do_mfma<0, 1>(acc, aF, bF1);
    VMCNT6; FENCE; __builtin_amdgcn_s_barrier();

    // ---- p2: loadA half1 (8); q(1,0) w/ bF0; stage Ah0(t+2)->CURRENT (free after p0) ----
    loadA<1>(Ac, wm, lo, g0, q, aF);
    stageA(As2, Acw, 0, w, l); stageA(As2, Acw, 128, w, l);
    FENCE; __builtin_amdgcn_s_barrier();
    LGKM0; __builtin_amdgcn_sched_barrier(0);
    do_mfma<1, 0>(acc, aF, bF0);
    VMCNT6; FENCE; __builtin_amdgcn_s_barrier();

    // ---- p3: preload bF0(t+1) from OTHER buf (4); q(1,1); stage Bh0(t+2)->CURRENT ----
    loadB<0>(Bnr, wn, lo, g0, q, bF0);
    stageB(Bs2, Bcw, 0, 0, w, l); stageB(Bs2, Bcw, 0, 1, w, l);
    FENCE; __builtin_amdgcn_s_barrier();
    LGKM0; __builtin_amdgcn_sched_barrier(0);
    do_mfma<1, 1>(acc, aF, bF1);
    VMCNT6; FENCE; __builtin_amdgcn_s_barrier();
  }

  // drain in-flight wrap stages before reusing LDS as reduction scratch
  VMCNT0; FENCE;
  __builtin_amdgcn_s_barrier();

  // ---- epilogue: per-row sum(exp) over this 256-col tile + gt extraction ----
  float* red = (float*)&Abuf[0][0][0];
#pragma unroll
  for (int m = 0; m < 8; m++) {
#pragma unroll
    for (int j = 0; j < 4; j++) {
      const int rloc = wm * 128 + m * 16 + hi * 4 + j;
      const int gr = rowBase + rloc;
      const int te = teff[gr];
      float s = 0.f;
#pragma unroll
      for (int n = 0; n < 4; n++) {
        float v = acc[m][n][j];
        const int gc = colBase + wn * 64 + n * 16 + lo;
        if (te == gc) gt[gr] = v;
        s += __expf(v);
      }
#pragma unroll
      for (int d = 1; d < 16; d <<= 1) s += __shfl_xor(s, d);
      if (lo == 0) red[wn * 256 + rloc] = s;
    }
  }
  __syncthreads();
  if (tid < 256) {
    float S = red[tid] + red[256 + tid] + red[512 + tid] + red[768 + tid];
    partial[(size_t)(rowBase + tid) * NTN + by] = S;
  }
}

// ---- combine 125 tile partials per row -> per-token loss ----
__global__ void reduce_lse(const float* __restrict__ partial, const float* __restrict__ gt,
                           const int* __restrict__ ign, const float* __restrict__ divisor,
                           float* __restrict__ pertok) {
  int r = blockIdx.x * 4 + (threadIdx.x >> 6);
  int l = threadIdx.x & 63;
  float S = 0.f;
  for (int p = l; p < NTN; p += 64) S += partial[(size_t)r * NTN + p];
#pragma unroll
  for (int d = 1; d < 64; d <<= 1) S += __shfl_xor(S, d);
  if (l == 0) {
    float lse = __logf(S);
    pertok[r] = ign[r] ? 0.f : (lse - gt[r]) / divisor[0];
  }
}

// ---- deterministic final sum ----
__global__ void final_sum(const float* __restrict__ pertok, float* __restrict__ out) {
  __shared__ float red[16];
  float s = 0.f;
  for (int i = threadIdx.x; i < N_TOK; i += 1024) s += pertok[i];
#pragma unroll
  for (int d = 1; d < 64; d <<= 1) s += __shfl_xor(s, d);
  if ((threadIdx.x & 63) == 0) red[threadIdx.x >> 6] = s;
  __syncthreads();
  if (threadIdx.x == 0) {
    float t = 0.f;
    for (int i = 0; i < 16; i++) t += red[i];
    out[0] = t;
  }
}

extern "C" void kernel_launch(void* const* d_in, const int* in_sizes, int n_in,
                              void* d_out, int out_size, void* d_ws, size_t ws_size,
                              hipStream_t stream) {
  const float* x = (const float*)d_in[0];       // [4096,1024] f32
  const float* w = (const float*)d_in[1];       // [32000,1024] f32
  const int* targ = (const int*)d_in[2];        // [4096] int
  float* out = (float*)d_out;

  char* ws = (char*)d_ws;
  u8*    Xf8     = (u8*)(ws);                      // 4,194,304 B
  u8*    Wf8     = (u8*)(ws + 4194304);            // 32,768,000 B
  float* partial = (float*)(ws + 36962304);        // 2,048,000 B
  float* gt      = (float*)(ws + 39010304);        // 16,384 B
  int*   teff    = (int*)(ws + 39026688);          // 16,384 B
  int*   ign     = (int*)(ws + 39043072);          // 16,384 B
  float* divisor = (float*)(ws + 39059456);        // 256 B
  float* pertok  = (float*)(ws + 39059712);        // 16,384 B

  {
    int n8 = N_TOK * DIM / 8;                      // 524288
    cvt_fp8<<<(n8 + 255) / 256, 256, 0, stream>>>((const float4*)x, (uint2*)Xf8, n8);
  }
  {
    int n8 = NCLS * DIM / 8;                       // 4,096,000
    cvt_fp8<<<(n8 + 255) / 256, 256, 0, stream>>>((const float4*)w, (uint2*)Wf8, n8);
  }
  prep_targ<<<1, 1024, 0, stream>>>(targ, teff, ign, divisor);

  gemm_lse<<<NTM * NTN, 512, 0, stream>>>(Xf8, Wf8, teff, gt, partial);  // 2000 blocks

  reduce_lse<<<N_TOK / 4, 256, 0, stream>>>(partial, gt, ign, divisor, pertok);
  final_sum<<<1, 1024, 0, stream>>>(pertok, out);
}